// Round 1
// baseline (5280.234 us; speedup 1.0000x reference)
//
#include <hip/hip_runtime.h>

#define N_TOK 131072
#define D_INP 256
#define D_HID 512
#define D_OUTP 256
#define NEXP 8

typedef unsigned short u16;
using short8  = __attribute__((ext_vector_type(8))) short;
using floatx4 = __attribute__((ext_vector_type(4))) float;

static __device__ __forceinline__ u16 f2bf(float f) {
  unsigned u = __float_as_uint(f);
  u = (u + 0x7fffu + ((u >> 16) & 1u)) >> 16;   // round-to-nearest-even
  return (u16)u;
}
static __device__ __forceinline__ float gelu_exact(float v) {
  return 0.5f * v * (1.0f + erff(v * 0.70710678118654752f));
}

// ---------------------------------------------------------------------------
// Gating: one wave per token. logits = tanh(x@gw1) @ gw2 ; softmax ; top-2 ;
// renormalize ; write dense comb[N][8]. Also casts x -> bf16 (fused).
// ---------------------------------------------------------------------------
__global__ __launch_bounds__(256) void gate_cast(
    const float* __restrict__ x, const float* __restrict__ gw1,
    const float* __restrict__ gw2, u16* __restrict__ xb,
    float* __restrict__ comb) {
  const int lane  = threadIdx.x & 63;
  const int token = blockIdx.x * 4 + (threadIdx.x >> 6);

  const float4 v = ((const float4*)(x + (size_t)token * D_INP))[lane];

  // fused bf16 cast of x
  ushort4 b4;
  b4.x = f2bf(v.x); b4.y = f2bf(v.y); b4.z = f2bf(v.z); b4.w = f2bf(v.w);
  *(ushort4*)(xb + (size_t)token * D_INP + lane * 4) = b4;

  // hidden = x @ gw1  (each lane: 4 input dims x 16 outputs, then wave reduce)
  float p[16];
#pragma unroll
  for (int j = 0; j < 16; ++j) p[j] = 0.f;
  const float va[4] = {v.x, v.y, v.z, v.w};
  const int d0 = lane * 4;
#pragma unroll
  for (int r = 0; r < 4; ++r) {
    const float xr = va[r];
    const float4* g4 = (const float4*)(gw1 + (size_t)(d0 + r) * 16);
    float4 a0 = g4[0], a1 = g4[1], a2 = g4[2], a3 = g4[3];
    p[0]  += xr * a0.x; p[1]  += xr * a0.y; p[2]  += xr * a0.z; p[3]  += xr * a0.w;
    p[4]  += xr * a1.x; p[5]  += xr * a1.y; p[6]  += xr * a1.z; p[7]  += xr * a1.w;
    p[8]  += xr * a2.x; p[9]  += xr * a2.y; p[10] += xr * a2.z; p[11] += xr * a2.w;
    p[12] += xr * a3.x; p[13] += xr * a3.y; p[14] += xr * a3.z; p[15] += xr * a3.w;
  }
#pragma unroll
  for (int m = 1; m < 64; m <<= 1) {
#pragma unroll
    for (int j = 0; j < 16; ++j) p[j] += __shfl_xor(p[j], m, 64);
  }
  float tj[16];
#pragma unroll
  for (int j = 0; j < 16; ++j) tj[j] = tanhf(p[j]);

  float lg[8];
#pragma unroll
  for (int e = 0; e < 8; ++e) {
    float s = 0.f;
#pragma unroll
    for (int j = 0; j < 16; ++j) s += tj[j] * gw2[j * 8 + e];
    lg[e] = s;
  }
  // softmax
  float mx = lg[0];
#pragma unroll
  for (int e = 1; e < 8; ++e) mx = fmaxf(mx, lg[e]);
  float ex[8], se = 0.f;
#pragma unroll
  for (int e = 0; e < 8; ++e) { ex[e] = expf(lg[e] - mx); se += ex[e]; }
  float inv = 1.f / se;
#pragma unroll
  for (int e = 0; e < 8; ++e) ex[e] *= inv;
  // top-2 (first occurrence wins ties, matches lax.top_k)
  int i1 = 0; float v1 = ex[0];
#pragma unroll
  for (int e = 1; e < 8; ++e) if (ex[e] > v1) { v1 = ex[e]; i1 = e; }
  int i2 = -1; float v2 = -1.f;
#pragma unroll
  for (int e = 0; e < 8; ++e) if (e != i1 && ex[e] > v2) { v2 = ex[e]; i2 = e; }
  float rs = 1.f / (v1 + v2 + 1e-12f);
  float w1 = v1 * rs, w2 = v2 * rs;

  if (lane < 8) {
    float w = (lane == i1) ? w1 : ((lane == i2) ? w2 : 0.f);
    comb[(size_t)token * 8 + lane] = w;
  }
}

// ---------------------------------------------------------------------------
// Transpose + cast weights: W[e][k][n] (fp32) -> Wt[e][n][k] (bf16)
// ---------------------------------------------------------------------------
__global__ __launch_bounds__(256) void transpose_cast(
    const float* __restrict__ W, u16* __restrict__ Wt, int K, int Nw) {
  __shared__ float tile[64][65];
  const int k0 = blockIdx.x * 64, n0 = blockIdx.y * 64, e = blockIdx.z;
  const float* Wp = W + (size_t)e * K * Nw;
  u16* Wtp = Wt + (size_t)e * K * Nw;
#pragma unroll
  for (int i = 0; i < 16; ++i) {
    int idx = threadIdx.x + i * 256;
    int r = idx >> 6, c = idx & 63;
    tile[r][c] = Wp[(size_t)(k0 + r) * Nw + n0 + c];
  }
  __syncthreads();
#pragma unroll
  for (int i = 0; i < 16; ++i) {
    int idx = threadIdx.x + i * 256;
    int r = idx >> 6, c = idx & 63;
    Wtp[(size_t)(n0 + r) * K + k0 + c] = f2bf(tile[c][r]);
  }
}

// ---------------------------------------------------------------------------
// GEMM + bias + LayerNorm + GELU, bf16 in/out, fp32 accum.
// Block tile: 32 rows x 512 cols (full LN row in-block). 4 waves, each wave
// 32 rows x 128 cols = 2x8 frags of 16x16, MFMA 16x16x32 bf16, BK=32.
// LDS fragment-order layout [quad][n][8] -> conflict-light ds_read_b128.
// ---------------------------------------------------------------------------
template <int KD>
__global__ __launch_bounds__(256) void gemm_ln_gelu(
    const u16* __restrict__ A, const u16* __restrict__ Wt,
    const float* __restrict__ bias, const float* __restrict__ gam,
    const float* __restrict__ bet, u16* __restrict__ H) {
  __shared__ u16 As[4][32][8];
  __shared__ u16 Ws[4][512][8];
  __shared__ float redS[32][4];
  __shared__ float redQ[32][4];
  const int t = threadIdx.x;
  const int lane = t & 63, wv = t >> 6;
  const int cl = lane & 15, qd = lane >> 4;
  const int cb = wv * 128;
  const int r0 = blockIdx.x * 32;

  floatx4 acc[2][8];
#pragma unroll
  for (int rt = 0; rt < 2; ++rt)
#pragma unroll
    for (int c = 0; c < 8; ++c) acc[rt][c] = (floatx4){0.f, 0.f, 0.f, 0.f};

  for (int kt = 0; kt < KD / 32; ++kt) {
    if (t < 128) {
      int m = t >> 2, q = t & 3;
      *(uint4*)(&As[q][m][0]) =
          *(const uint4*)(&A[(size_t)(r0 + m) * KD + kt * 32 + q * 8]);
    }
#pragma unroll
    for (int i = 0; i < 8; ++i) {
      int idx = t + i * 256;
      int n = idx >> 2, q = idx & 3;
      *(uint4*)(&Ws[q][n][0]) =
          *(const uint4*)(&Wt[(size_t)n * KD + kt * 32 + q * 8]);
    }
    __syncthreads();
    short8 a0 = *(const short8*)(&As[qd][cl][0]);
    short8 a1 = *(const short8*)(&As[qd][16 + cl][0]);
#pragma unroll
    for (int c = 0; c < 8; ++c) {
      short8 bfr = *(const short8*)(&Ws[qd][cb + c * 16 + cl][0]);
      acc[0][c] = __builtin_amdgcn_mfma_f32_16x16x32_bf16(a0, bfr, acc[0][c], 0, 0, 0);
      acc[1][c] = __builtin_amdgcn_mfma_f32_16x16x32_bf16(a1, bfr, acc[1][c], 0, 0, 0);
    }
    __syncthreads();
  }

  // + bias (before LN: reference is LN(x@W + b))
#pragma unroll
  for (int c = 0; c < 8; ++c) {
    float bv = bias[cb + c * 16 + cl];
#pragma unroll
    for (int rt = 0; rt < 2; ++rt)
#pragma unroll
      for (int r = 0; r < 4; ++r) acc[rt][c][r] += bv;
  }

  // row stats: in-register over 8 col-frags, shuffle over 16 col-lanes,
  // LDS over the 4 waves.
#pragma unroll
  for (int rt = 0; rt < 2; ++rt)
#pragma unroll
    for (int r = 0; r < 4; ++r) {
      float s = 0.f, q2 = 0.f;
#pragma unroll
      for (int c = 0; c < 8; ++c) { float v = acc[rt][c][r]; s += v; q2 += v * v; }
#pragma unroll
      for (int m = 1; m < 16; m <<= 1) {
        s += __shfl_xor(s, m, 64);
        q2 += __shfl_xor(q2, m, 64);
      }
      if (cl == 0) {
        int row = rt * 16 + qd * 4 + r;
        redS[row][wv] = s;
        redQ[row][wv] = q2;
      }
    }
  __syncthreads();
  float mean[2][4], rstd[2][4];
#pragma unroll
  for (int rt = 0; rt < 2; ++rt)
#pragma unroll
    for (int r = 0; r < 4; ++r) {
      int row = rt * 16 + qd * 4 + r;
      float s = redS[row][0] + redS[row][1] + redS[row][2] + redS[row][3];
      float q2 = redQ[row][0] + redQ[row][1] + redQ[row][2] + redQ[row][3];
      float mu = s * (1.f / 512.f);
      float var = q2 * (1.f / 512.f) - mu * mu;
      mean[rt][r] = mu;
      rstd[rt][r] = rsqrtf(var + 1e-5f);
    }
#pragma unroll
  for (int c = 0; c < 8; ++c) {
    int col = cb + c * 16 + cl;
    float ga = gam[col], be = bet[col];
#pragma unroll
    for (int rt = 0; rt < 2; ++rt)
#pragma unroll
      for (int r = 0; r < 4; ++r) {
        float v = (acc[rt][c][r] - mean[rt][r]) * rstd[rt][r] * ga + be;
        int row = r0 + rt * 16 + qd * 4 + r;
        H[(size_t)row * 512 + col] = f2bf(gelu_exact(v));
      }
  }
}

// ---------------------------------------------------------------------------
// GEMM3: y = h @ W3 + b3 ; out += comb[:,e] * y.  Tile 32 x 256, 4 waves
// (each 32 rows x 64 cols). Skips RMW when combine weight is zero.
// ---------------------------------------------------------------------------
__global__ __launch_bounds__(256) void gemm3_combine(
    const u16* __restrict__ A, const u16* __restrict__ Wt,
    const float* __restrict__ b3, const float* __restrict__ comb, int e,
    float* __restrict__ out) {
  __shared__ u16 As[4][32][8];
  __shared__ u16 Ws[4][256][8];
  const int t = threadIdx.x;
  const int lane = t & 63, wv = t >> 6;
  const int cl = lane & 15, qd = lane >> 4;
  const int cb = wv * 64;
  const int r0 = blockIdx.x * 32;

  floatx4 acc[2][4];
#pragma unroll
  for (int rt = 0; rt < 2; ++rt)
#pragma unroll
    for (int c = 0; c < 4; ++c) acc[rt][c] = (floatx4){0.f, 0.f, 0.f, 0.f};

  for (int kt = 0; kt < 16; ++kt) {
    if (t < 128) {
      int m = t >> 2, q = t & 3;
      *(uint4*)(&As[q][m][0]) =
          *(const uint4*)(&A[(size_t)(r0 + m) * 512 + kt * 32 + q * 8]);
    }
#pragma unroll
    for (int i = 0; i < 4; ++i) {
      int idx = t + i * 256;
      int n = idx >> 2, q = idx & 3;
      *(uint4*)(&Ws[q][n][0]) =
          *(const uint4*)(&Wt[(size_t)n * 512 + kt * 32 + q * 8]);
    }
    __syncthreads();
    short8 a0 = *(const short8*)(&As[qd][cl][0]);
    short8 a1 = *(const short8*)(&As[qd][16 + cl][0]);
#pragma unroll
    for (int c = 0; c < 4; ++c) {
      short8 bfr = *(const short8*)(&Ws[qd][cb + c * 16 + cl][0]);
      acc[0][c] = __builtin_amdgcn_mfma_f32_16x16x32_bf16(a0, bfr, acc[0][c], 0, 0, 0);
      acc[1][c] = __builtin_amdgcn_mfma_f32_16x16x32_bf16(a1, bfr, acc[1][c], 0, 0, 0);
    }
    __syncthreads();
  }
#pragma unroll
  for (int rt = 0; rt < 2; ++rt)
#pragma unroll
    for (int r = 0; r < 4; ++r) {
      int row = r0 + rt * 16 + qd * 4 + r;
      float w = comb[(size_t)row * 8 + e];
      if (w != 0.f) {
#pragma unroll
        for (int c = 0; c < 4; ++c) {
          int col = cb + c * 16 + cl;
          float y = acc[rt][c][r] + b3[col];
          out[(size_t)row * 256 + col] += w * y;
        }
      }
    }
}

// ---------------------------------------------------------------------------
// Launcher. ws layout (bytes):
//   xb   @ 0          : N*256*2  = 67,108,864
//   h    @ 67108864   : N*512*2  = 134,217,728   (GEMM2 runs in-place)
//   comb @ 201326592  : N*8*4    = 4,194,304
//   W1t  @ 205520896  : 8*512*256*2 = 2,097,152
//   W2t  @ 207618048  : 8*512*512*2 = 4,194,304
//   W3t  @ 211812352  : 8*256*512*2 = 2,097,152   (total ~214 MB)
// ---------------------------------------------------------------------------
extern "C" void kernel_launch(void* const* d_in, const int* in_sizes, int n_in,
                              void* d_out, int out_size, void* d_ws,
                              size_t ws_size, hipStream_t stream) {
  const float* x   = (const float*)d_in[0];
  const float* gw1 = (const float*)d_in[1];
  const float* gw2 = (const float*)d_in[2];
  const float* W1  = (const float*)d_in[3];
  const float* b1  = (const float*)d_in[4];
  const float* g1  = (const float*)d_in[5];
  const float* be1 = (const float*)d_in[6];
  const float* W2  = (const float*)d_in[7];
  const float* b2  = (const float*)d_in[8];
  const float* g2  = (const float*)d_in[9];
  const float* be2 = (const float*)d_in[10];
  const float* W3  = (const float*)d_in[11];
  const float* b3  = (const float*)d_in[12];
  float* out = (float*)d_out;

  char* ws = (char*)d_ws;
  u16*   xb   = (u16*)(ws);
  u16*   h    = (u16*)(ws + 67108864);
  float* comb = (float*)(ws + 201326592);
  u16*   W1t  = (u16*)(ws + 205520896);
  u16*   W2t  = (u16*)(ws + 207618048);
  u16*   W3t  = (u16*)(ws + 211812352);

  hipMemsetAsync(d_out, 0, (size_t)N_TOK * D_OUTP * sizeof(float), stream);

  gate_cast<<<N_TOK / 4, 256, 0, stream>>>(x, gw1, gw2, xb, comb);

  transpose_cast<<<dim3(D_INP / 64, D_HID / 64, NEXP), 256, 0, stream>>>(
      W1, W1t, D_INP, D_HID);
  transpose_cast<<<dim3(D_HID / 64, D_HID / 64, NEXP), 256, 0, stream>>>(
      W2, W2t, D_HID, D_HID);
  transpose_cast<<<dim3(D_HID / 64, D_OUTP / 64, NEXP), 256, 0, stream>>>(
      W3, W3t, D_HID, D_OUTP);

  for (int e = 0; e < NEXP; ++e) {
    gemm_ln_gelu<D_INP><<<N_TOK / 32, 256, 0, stream>>>(
        xb, W1t + (size_t)e * D_HID * D_INP, b1 + e * D_HID, g1 + e * D_HID,
        be1 + e * D_HID, h);
    gemm_ln_gelu<D_HID><<<N_TOK / 32, 256, 0, stream>>>(
        h, W2t + (size_t)e * D_HID * D_HID, b2 + e * D_HID, g2 + e * D_HID,
        be2 + e * D_HID, h);
    gemm3_combine<<<N_TOK / 32, 256, 0, stream>>>(
        h, W3t + (size_t)e * D_OUTP * D_HID, b3 + e * D_OUTP, comb, e, out);
  }
}

// Round 2
// 3506.467 us; speedup vs baseline: 1.5059x; 1.5059x over previous
//
#include <hip/hip_runtime.h>

#define N_TOK 131072
#define D_INP 256
#define D_HID 512
#define D_OUTP 256
#define NEXP 8

typedef unsigned short u16;
using short8  = __attribute__((ext_vector_type(8))) short;
using floatx4 = __attribute__((ext_vector_type(4))) float;

static __device__ __forceinline__ u16 f2bf(float f) {
  unsigned u = __float_as_uint(f);
  u = (u + 0x7fffu + ((u >> 16) & 1u)) >> 16;   // round-to-nearest-even
  return (u16)u;
}
static __device__ __forceinline__ float gelu_exact(float v) {
  return 0.5f * v * (1.0f + erff(v * 0.70710678118654752f));
}
// async global->LDS, 16B per lane; dest must be wave-uniform base + lane*16
static __device__ __forceinline__ void gload16(const void* g, void* l) {
  __builtin_amdgcn_global_load_lds(
      (const __attribute__((address_space(1))) void*)g,
      (__attribute__((address_space(3))) void*)l, 16, 0, 0);
}

// ---------------------------------------------------------------------------
// Gating: one wave per token. logits = tanh(x@gw1) @ gw2 ; softmax ; top-2 ;
// renormalize. Writes (e1,e2) + (w1,w2) per token. Also casts x -> bf16.
// ---------------------------------------------------------------------------
__global__ __launch_bounds__(256) void gate_cast(
    const float* __restrict__ x, const float* __restrict__ gw1,
    const float* __restrict__ gw2, u16* __restrict__ xb,
    int2* __restrict__ tope, float2* __restrict__ wts) {
  const int lane  = threadIdx.x & 63;
  const int token = blockIdx.x * 4 + (threadIdx.x >> 6);

  const float4 v = ((const float4*)(x + (size_t)token * D_INP))[lane];

  ushort4 b4;
  b4.x = f2bf(v.x); b4.y = f2bf(v.y); b4.z = f2bf(v.z); b4.w = f2bf(v.w);
  *(ushort4*)(xb + (size_t)token * D_INP + lane * 4) = b4;

  float p[16];
#pragma unroll
  for (int j = 0; j < 16; ++j) p[j] = 0.f;
  const float va[4] = {v.x, v.y, v.z, v.w};
  const int d0 = lane * 4;
#pragma unroll
  for (int r = 0; r < 4; ++r) {
    const float xr = va[r];
    const float4* g4 = (const float4*)(gw1 + (size_t)(d0 + r) * 16);
    float4 a0 = g4[0], a1 = g4[1], a2 = g4[2], a3 = g4[3];
    p[0]  += xr * a0.x; p[1]  += xr * a0.y; p[2]  += xr * a0.z; p[3]  += xr * a0.w;
    p[4]  += xr * a1.x; p[5]  += xr * a1.y; p[6]  += xr * a1.z; p[7]  += xr * a1.w;
    p[8]  += xr * a2.x; p[9]  += xr * a2.y; p[10] += xr * a2.z; p[11] += xr * a2.w;
    p[12] += xr * a3.x; p[13] += xr * a3.y; p[14] += xr * a3.z; p[15] += xr * a3.w;
  }
#pragma unroll
  for (int m = 1; m < 64; m <<= 1) {
#pragma unroll
    for (int j = 0; j < 16; ++j) p[j] += __shfl_xor(p[j], m, 64);
  }
  float tj[16];
#pragma unroll
  for (int j = 0; j < 16; ++j) tj[j] = tanhf(p[j]);

  float lg[8];
#pragma unroll
  for (int e = 0; e < 8; ++e) {
    float s = 0.f;
#pragma unroll
    for (int j = 0; j < 16; ++j) s += tj[j] * gw2[j * 8 + e];
    lg[e] = s;
  }
  float mx = lg[0];
#pragma unroll
  for (int e = 1; e < 8; ++e) mx = fmaxf(mx, lg[e]);
  float ex[8], se = 0.f;
#pragma unroll
  for (int e = 0; e < 8; ++e) { ex[e] = expf(lg[e] - mx); se += ex[e]; }
  float inv = 1.f / se;
#pragma unroll
  for (int e = 0; e < 8; ++e) ex[e] *= inv;
  int i1 = 0; float v1 = ex[0];
#pragma unroll
  for (int e = 1; e < 8; ++e) if (ex[e] > v1) { v1 = ex[e]; i1 = e; }
  int i2 = -1; float v2 = -1.f;
#pragma unroll
  for (int e = 0; e < 8; ++e) if (e != i1 && ex[e] > v2) { v2 = ex[e]; i2 = e; }
  float rs = 1.f / (v1 + v2 + 1e-12f);

  if (lane == 0) {
    tope[token] = make_int2(i1, i2);
    wts[token]  = make_float2(v1 * rs, v2 * rs);
  }
}

// ---------------------------------------------------------------------------
// Routing: count per-expert (wave-aggregated), scan (padded to 64), assign.
// ---------------------------------------------------------------------------
__global__ __launch_bounds__(256) void count_k(const int2* __restrict__ tope,
                                               int* __restrict__ counts) {
  int t = blockIdx.x * 256 + threadIdx.x;
  int lane = threadIdx.x & 63;
  int2 ee = tope[t];
#pragma unroll
  for (int e = 0; e < 8; ++e) {
    unsigned long long m1 = __ballot(ee.x == e);
    unsigned long long m2 = __ballot(ee.y == e);
    int c = __popcll(m1) + __popcll(m2);
    if (lane == 0 && c) atomicAdd(counts + e, c);
  }
}

__global__ void scan_k(const int* __restrict__ counts, int* __restrict__ off) {
  if (threadIdx.x == 0 && blockIdx.x == 0) {
    int o = 0;
    for (int e = 0; e < 8; ++e) { off[e] = o; o += (counts[e] + 63) & ~63; }
    off[8] = o;
  }
}

__global__ __launch_bounds__(256) void assign_k(
    const int2* __restrict__ tope, const float2* __restrict__ wts,
    const int* __restrict__ off, int* __restrict__ cursors,
    int* __restrict__ perm, float* __restrict__ wgt) {
  int t = blockIdx.x * 256 + threadIdx.x;
  int lane = threadIdx.x & 63;
  int2 ee = tope[t];
  float2 ww = wts[t];
  unsigned long long lt = (lane == 63) ? 0x7fffffffffffffffULL
                                       : ((1ULL << lane) - 1ULL);
#pragma unroll
  for (int k = 0; k < 2; ++k) {
    int e = k ? ee.y : ee.x;
    float w = k ? ww.y : ww.x;
#pragma unroll
    for (int q = 0; q < 8; ++q) {
      unsigned long long mask = __ballot(e == q);
      if (!mask) continue;
      int leader = __ffsll((long long)mask) - 1;
      int base = 0;
      if (lane == leader) base = atomicAdd(cursors + q, __popcll(mask));
      base = __shfl(base, leader);
      if (e == q) {
        int pos = base + __popcll(mask & lt);
        int slot = off[q] + pos;
        perm[slot] = t;
        wgt[slot] = w;
      }
    }
  }
}

// ---------------------------------------------------------------------------
// Weight prep: W[e][k][n] fp32 -> LDS-image bf16 img[e][kt][q][n][8],
// element (k = kt*32 + q*8 + j, n). Staging then = pure linear copy.
// ---------------------------------------------------------------------------
template <int NW>
__global__ __launch_bounds__(256) void wprep(const float* __restrict__ W,
                                             u16* __restrict__ img, int K) {
  const int e = blockIdx.z, kt = blockIdx.x;
  const int chunks = 4 * NW;
  const float* Wp = W + (size_t)e * K * NW;
  u16* ip = img + ((size_t)e * (K / 32) + kt) * (size_t)chunks * 8;
  for (int idx = threadIdx.x; idx < chunks; idx += 256) {
    int q = idx / NW, n = idx % NW;
    int k0 = kt * 32 + q * 8;
    u16 tmp[8];
#pragma unroll
    for (int j = 0; j < 8; ++j) tmp[j] = f2bf(Wp[(size_t)(k0 + j) * NW + n]);
    *(uint4*)(ip + (size_t)idx * 8) = *(uint4*)tmp;
  }
}

// ---------------------------------------------------------------------------
// Fused routed expert: per 64-slot tile, x ->(GEMM1+LN+GELU)-> h1(LDS)
// ->(GEMM2+LN+GELU)-> h2(LDS, in place) ->(GEMM3+bias)-> atomic scatter to out.
// 512 threads = 8 waves; wave covers 64 rows x 64 cols (GEMM1/2), x 32 (GEMM3).
// ---------------------------------------------------------------------------
__device__ __forceinline__ void ln_gelu_epi(
    floatx4 (&acc)[4][4], const float* __restrict__ bias,
    const float* __restrict__ gam, const float* __restrict__ bet,
    u16* Hs, float* redS, float* redQ, int wv, int cl, int qd) {
#pragma unroll
  for (int c = 0; c < 4; ++c) {
    float bv = bias[wv * 64 + c * 16 + cl];
#pragma unroll
    for (int rt = 0; rt < 4; ++rt)
#pragma unroll
      for (int r = 0; r < 4; ++r) acc[rt][c][r] += bv;
  }
#pragma unroll
  for (int rt = 0; rt < 4; ++rt)
#pragma unroll
    for (int r = 0; r < 4; ++r) {
      float s = 0.f, q2 = 0.f;
#pragma unroll
      for (int c = 0; c < 4; ++c) { float v = acc[rt][c][r]; s += v; q2 += v * v; }
#pragma unroll
      for (int m = 1; m < 16; m <<= 1) {
        s += __shfl_xor(s, m, 64);
        q2 += __shfl_xor(q2, m, 64);
      }
      if (cl == 0) {
        int row = rt * 16 + qd * 4 + r;
        redS[row * 8 + wv] = s;
        redQ[row * 8 + wv] = q2;
      }
    }
  __syncthreads();
  float mean[4][4], rstd[4][4];
#pragma unroll
  for (int rt = 0; rt < 4; ++rt)
#pragma unroll
    for (int r = 0; r < 4; ++r) {
      int row = rt * 16 + qd * 4 + r;
      float s = 0.f, q2 = 0.f;
#pragma unroll
      for (int w = 0; w < 8; ++w) { s += redS[row * 8 + w]; q2 += redQ[row * 8 + w]; }
      float mu = s * (1.f / 512.f);
      float var = q2 * (1.f / 512.f) - mu * mu;
      mean[rt][r] = mu;
      rstd[rt][r] = rsqrtf(var + 1e-5f);
    }
#pragma unroll
  for (int c = 0; c < 4; ++c) {
    int col = wv * 64 + c * 16 + cl;
    float ga = gam[col], be = bet[col];
    int kt2 = col >> 5, q2i = (col >> 3) & 3, j = col & 7;
    u16* dst = Hs + (((kt2 * 4 + q2i) * 64) * 8) + j;
#pragma unroll
    for (int rt = 0; rt < 4; ++rt)
#pragma unroll
      for (int r = 0; r < 4; ++r) {
        int row = rt * 16 + qd * 4 + r;
        float v = (acc[rt][c][r] - mean[rt][r]) * rstd[rt][r] * ga + be;
        dst[row * 8] = f2bf(gelu_exact(v));
      }
  }
}

__global__ __launch_bounds__(512, 2) void moe_fused(
    const u16* __restrict__ xb, const u16* __restrict__ W1i,
    const u16* __restrict__ W2i, const u16* __restrict__ W3i,
    const float* __restrict__ b1, const float* __restrict__ g1,
    const float* __restrict__ be1, const float* __restrict__ b2,
    const float* __restrict__ g2, const float* __restrict__ be2,
    const float* __restrict__ b3, const int* __restrict__ off,
    const int* __restrict__ counts, const int* __restrict__ perm,
    const float* __restrict__ wgt, float* __restrict__ out) {
  extern __shared__ __align__(16) char smem[];
  u16*   Axf  = (u16*)smem;                  // [8][4][64][8]  32 KB
  u16*   Hs   = (u16*)(smem + 32768);        // [16][4][64][8] 64 KB
  u16*   Wst  = (u16*)(smem + 98304);        // [4][512][8]    32 KB
  float* redS = (float*)(smem + 131072);     // [64][8]         2 KB
  float* redQ = (float*)(smem + 133120);     //                 2 KB
  int*   sTok = (int*)(smem + 135168);       // [64]
  float* sW   = (float*)(smem + 135424);     // [64]

  const int t = threadIdx.x, lane = t & 63, wv = t >> 6;
  const int cl = lane & 15, qd = lane >> 4;
  const int r0 = blockIdx.x * 64;

  int e = 0;
#pragma unroll
  for (int i = 1; i < 8; ++i) if (r0 >= off[i]) e = i;
  if (r0 >= off[8]) return;
  const int end = off[e] + counts[e];

  if (t < 64) {
    int slot = r0 + t;
    bool v = slot < end;
    sTok[t] = v ? perm[slot] : 0;
    sW[t]   = v ? wgt[slot]  : 0.f;
  }
  __syncthreads();

  // gather x rows -> Axf  [kt][q][m][8], dest linear in (t + i*512)
  {
    const int m = t & 63;
    const u16* src = xb + (size_t)sTok[m] * 256;
#pragma unroll
    for (int i = 0; i < 4; ++i) {
      int c = (t >> 6) + i * 8;                 // 0..31
      gload16(src + c * 8, Axf + (size_t)(c * 64 + m) * 8);
    }
  }

  floatx4 acc[4][4];
#pragma unroll
  for (int rt = 0; rt < 4; ++rt)
#pragma unroll
    for (int c = 0; c < 4; ++c) acc[rt][c] = (floatx4){0.f, 0.f, 0.f, 0.f};

  // ---- GEMM1: K=256 (8 k-tiles) ----
  for (int kt = 0; kt < 8; ++kt) {
    const u16* wsrc = W1i + ((size_t)(e * 8 + kt) * 2048) * 8;
#pragma unroll
    for (int i = 0; i < 4; ++i) {
      int idx = t + i * 512;
      gload16(wsrc + (size_t)idx * 8, Wst + (size_t)idx * 8);
    }
    __syncthreads();
    short8 a[4];
#pragma unroll
    for (int rt = 0; rt < 4; ++rt)
      a[rt] = *(const short8*)(Axf + ((size_t)(kt * 4 + qd) * 64 + rt * 16 + cl) * 8);
#pragma unroll
    for (int c = 0; c < 4; ++c) {
      short8 b = *(const short8*)(Wst + ((size_t)qd * 512 + wv * 64 + c * 16 + cl) * 8);
#pragma unroll
      for (int rt = 0; rt < 4; ++rt)
        acc[rt][c] = __builtin_amdgcn_mfma_f32_16x16x32_bf16(a[rt], b, acc[rt][c], 0, 0, 0);
    }
    __syncthreads();
  }
  ln_gelu_epi(acc, b1 + e * D_HID, g1 + e * D_HID, be1 + e * D_HID,
              Hs, redS, redQ, wv, cl, qd);

#pragma unroll
  for (int rt = 0; rt < 4; ++rt)
#pragma unroll
    for (int c = 0; c < 4; ++c) acc[rt][c] = (floatx4){0.f, 0.f, 0.f, 0.f};

  // ---- GEMM2: K=512 (16 k-tiles), A = h1 from LDS ----
  for (int kt = 0; kt < 16; ++kt) {
    const u16* wsrc = W2i + ((size_t)(e * 16 + kt) * 2048) * 8;
#pragma unroll
    for (int i = 0; i < 4; ++i) {
      int idx = t + i * 512;
      gload16(wsrc + (size_t)idx * 8, Wst + (size_t)idx * 8);
    }
    __syncthreads();
    short8 a[4];
#pragma unroll
    for (int rt = 0; rt < 4; ++rt)
      a[rt] = *(const short8*)(Hs + ((size_t)(kt * 4 + qd) * 64 + rt * 16 + cl) * 8);
#pragma unroll
    for (int c = 0; c < 4; ++c) {
      short8 b = *(const short8*)(Wst + ((size_t)qd * 512 + wv * 64 + c * 16 + cl) * 8);
#pragma unroll
      for (int rt = 0; rt < 4; ++rt)
        acc[rt][c] = __builtin_amdgcn_mfma_f32_16x16x32_bf16(a[rt], b, acc[rt][c], 0, 0, 0);
    }
    __syncthreads();
  }
  ln_gelu_epi(acc, b2 + e * D_HID, g2 + e * D_HID, be2 + e * D_HID,
              Hs, redS, redQ, wv, cl, qd);
  __syncthreads();   // h2 writes visible before GEMM3 reads

  // ---- GEMM3: K=512, N=256; wave covers 64 rows x 32 cols ----
  floatx4 acc3[4][2];
#pragma unroll
  for (int rt = 0; rt < 4; ++rt)
#pragma unroll
    for (int c = 0; c < 2; ++c) acc3[rt][c] = (floatx4){0.f, 0.f, 0.f, 0.f};

  for (int kt = 0; kt < 16; ++kt) {
    const u16* wsrc = W3i + ((size_t)(e * 16 + kt) * 1024) * 8;
#pragma unroll
    for (int i = 0; i < 2; ++i) {
      int idx = t + i * 512;
      gload16(wsrc + (size_t)idx * 8, Wst + (size_t)idx * 8);
    }
    __syncthreads();
    short8 a[4];
#pragma unroll
    for (int rt = 0; rt < 4; ++rt)
      a[rt] = *(const short8*)(Hs + ((size_t)(kt * 4 + qd) * 64 + rt * 16 + cl) * 8);
#pragma unroll
    for (int c = 0; c < 2; ++c) {
      short8 b = *(const short8*)(Wst + ((size_t)qd * 256 + wv * 32 + c * 16 + cl) * 8);
#pragma unroll
      for (int rt = 0; rt < 4; ++rt)
        acc3[rt][c] = __builtin_amdgcn_mfma_f32_16x16x32_bf16(a[rt], b, acc3[rt][c], 0, 0, 0);
    }
    __syncthreads();
  }

  // epilogue 3: y = acc + b3 ; out[token] += w * y (atomic)
  float b3v[2];
#pragma unroll
  for (int c = 0; c < 2; ++c) b3v[c] = b3[e * D_OUTP + wv * 32 + c * 16 + cl];
#pragma unroll
  for (int rt = 0; rt < 4; ++rt)
#pragma unroll
    for (int r = 0; r < 4; ++r) {
      int sR = rt * 16 + qd * 4 + r;
      float w = sW[sR];
      if (w != 0.f) {
        float* obase = out + (size_t)sTok[sR] * 256;
#pragma unroll
        for (int c = 0; c < 2; ++c) {
          int col = wv * 32 + c * 16 + cl;
          atomicAdd(obase + col, w * (acc3[rt][c][r] + b3v[c]));
        }
      }
    }
}

// ---------------------------------------------------------------------------
// Launcher. ws layout (bytes):
//   xb    @ 0         : 67,108,864
//   W1img @ 67108864  : 2,097,152
//   W2img @ 69206016  : 4,194,304
//   W3img @ 73400320  : 2,097,152
//   tope  @ 75497472  : 1,048,576
//   wts   @ 76546048  : 1,048,576
//   perm  @ 77594624  : 1,051,648
//   wgt   @ 78646272  : 1,051,648
//   meta  @ 79697920  : counts[8] | cursors[8] | off[9]
// ---------------------------------------------------------------------------
extern "C" void kernel_launch(void* const* d_in, const int* in_sizes, int n_in,
                              void* d_out, int out_size, void* d_ws,
                              size_t ws_size, hipStream_t stream) {
  const float* x   = (const float*)d_in[0];
  const float* gw1 = (const float*)d_in[1];
  const float* gw2 = (const float*)d_in[2];
  const float* W1  = (const float*)d_in[3];
  const float* b1  = (const float*)d_in[4];
  const float* g1  = (const float*)d_in[5];
  const float* be1 = (const float*)d_in[6];
  const float* W2  = (const float*)d_in[7];
  const float* b2  = (const float*)d_in[8];
  const float* g2  = (const float*)d_in[9];
  const float* be2 = (const float*)d_in[10];
  const float* W3  = (const float*)d_in[11];
  const float* b3  = (const float*)d_in[12];
  float* out = (float*)d_out;

  char* ws = (char*)d_ws;
  u16*    xb   = (u16*)(ws);
  u16*    W1i  = (u16*)(ws + 67108864);
  u16*    W2i  = (u16*)(ws + 69206016);
  u16*    W3i  = (u16*)(ws + 73400320);
  int2*   tope = (int2*)(ws + 75497472);
  float2* wtsp = (float2*)(ws + 76546048);
  int*    perm = (int*)(ws + 77594624);
  float*  wgt  = (float*)(ws + 78646272);
  int*    meta = (int*)(ws + 79697920);
  int* counts  = meta;        // 8
  int* cursors = meta + 8;    // 8
  int* off     = meta + 16;   // 9

  static const int LDS_BYTES = 135680;
  hipFuncSetAttribute((const void*)moe_fused,
                      hipFuncAttributeMaxDynamicSharedMemorySize, LDS_BYTES);

  hipMemsetAsync(meta, 0, 64, stream);
  hipMemsetAsync(out, 0, (size_t)N_TOK * D_OUTP * sizeof(float), stream);

  gate_cast<<<N_TOK / 4, 256, 0, stream>>>(x, gw1, gw2, xb, tope, wtsp);
  count_k<<<N_TOK / 256, 256, 0, stream>>>(tope, counts);
  scan_k<<<1, 64, 0, stream>>>(counts, off);
  assign_k<<<N_TOK / 256, 256, 0, stream>>>(tope, wtsp, off, cursors, perm, wgt);

  wprep<512><<<dim3(8, 1, 8), 256, 0, stream>>>(W1, W1i, 256);
  wprep<512><<<dim3(16, 1, 8), 256, 0, stream>>>(W2, W2i, 512);
  wprep<256><<<dim3(16, 1, 8), 256, 0, stream>>>(W3, W3i, 512);

  const int nblk = (2 * N_TOK + NEXP * 63 + 63) / 64;   // 4104
  moe_fused<<<nblk, 512, LDS_BYTES, stream>>>(
      xb, W1i, W2i, W3i, b1, g1, be1, b2, g2, be2, b3,
      off, counts, perm, wgt, out);
}